// Round 2
// baseline (251.389 us; speedup 1.0000x reference)
//
#include <hip/hip_runtime.h>
#include <cmath>

typedef unsigned short u16;
typedef __attribute__((ext_vector_type(8))) short bf16x8;
typedef __attribute__((ext_vector_type(4))) float f32x4;

#define B_    2
#define SEQ_  2048
#define NH_   10
#define HD_   128
#define DIM_  1280

__device__ __forceinline__ u16 f2bf(float f) {
    union { float f; unsigned u; } v; v.f = f;
    unsigned r = (v.u + 0x7fffu + ((v.u >> 16) & 1u)) >> 16;
    return (u16)r;
}
__device__ __forceinline__ float bf2f(u16 h) {
    union { unsigned u; float f; } v; v.u = ((unsigned)h) << 16;
    return v.f;
}
__device__ __forceinline__ f32x4 mfma16(bf16x8 a, bf16x8 b, f32x4 c) {
    return __builtin_amdgcn_mfma_f32_16x16x32_bf16(a, b, c, 0, 0, 0);
}
__device__ __forceinline__ void g2l16(const void* g, void* l) {
    __builtin_amdgcn_global_load_lds(
        (const __attribute__((address_space(1))) unsigned*)g,
        (__attribute__((address_space(3))) unsigned*)l, 16, 0, 0);
}
__device__ __forceinline__ ushort4 pack4(float a, float b, float c, float d) {
    ushort4 w; w.x = f2bf(a); w.y = f2bf(b); w.z = f2bf(c); w.w = f2bf(d);
    return w;
}
// opaque LDS read: compiler can't see the LDS dependency -> no auto vmcnt(0)
// drain before it. Ordering vs global_load_lds is OUR job (counted vmcnt).
__device__ __forceinline__ bf16x8 ldsr128(unsigned byte_off) {
    bf16x8 r;
    asm volatile("ds_read_b128 %0, %1" : "=v"(r) : "v"(byte_off));
    return r;
}
__device__ __forceinline__ unsigned lds_off(const void* p) {
    return (unsigned)(unsigned long long)
        (__attribute__((address_space(3))) const void*)p;
}

// ---- merged convert + sincos: x + 4 weights -> bf16, then ct/st tables ----
__global__ __launch_bounds__(256) void cvt_k(const float* __restrict__ x,
                                             const float* __restrict__ w0,
                                             const float* __restrict__ w1,
                                             const float* __restrict__ w2,
                                             const float* __restrict__ w3,
                                             u16* __restrict__ xb,
                                             u16* __restrict__ d0,
                                             u16* __restrict__ d1,
                                             u16* __restrict__ d2,
                                             u16* __restrict__ d3,
                                             float* __restrict__ ct,
                                             float* __restrict__ st) {
    const int NX = B_ * SEQ_ * DIM_;          // 5,242,880
    const int WN = DIM_ * DIM_;               // 1,638,400
    const int NCV = (NX + 4 * WN) / 8 / 256;  // 5760 convert blocks
    int bid = blockIdx.x;
    if (bid >= NCV) {                          // sincos tail: 512 blocks
        int idx = (bid - NCV) * 256 + threadIdx.x;
        int s = idx >> 6, j = idx & 63;
        float e = (float)j * (1.0f / 64.0f);
        float theta = 1.0f / powf(10000.0f, e);
        float ang = (float)s * theta;
        ct[idx] = cosf(ang);
        st[idx] = sinf(ang);
        return;
    }
    int i = (bid * 256 + threadIdx.x) * 8;
    const float* src; u16* dst; int off;
    if (i < NX) { src = x; dst = xb; off = i; }
    else {
        int j = i - NX; int w = j / WN; off = j - w * WN;
        src = (w == 0) ? w0 : (w == 1) ? w1 : (w == 2) ? w2 : w3;
        dst = (w == 0) ? d0 : (w == 1) ? d1 : (w == 2) ? d2 : d3;
    }
    float4 a0 = *(const float4*)(src + off);
    float4 a1 = *(const float4*)(src + off + 4);
    union { uint4 q; u16 u[8]; } t;
    t.u[0] = f2bf(a0.x); t.u[1] = f2bf(a0.y);
    t.u[2] = f2bf(a0.z); t.u[3] = f2bf(a0.w);
    t.u[4] = f2bf(a1.x); t.u[5] = f2bf(a1.y);
    t.u[6] = f2bf(a1.z); t.u[7] = f2bf(a1.w);
    *(uint4*)(dst + off) = t.q;
}

// ------- legacy GEMM core (kept for out_gemm): 128x128 tile, BK=64 -------
template <typename OT>
__device__ __forceinline__ void gemm_core(const u16* __restrict__ A,
                                          const u16* __restrict__ W,
                                          const float* __restrict__ bias,
                                          OT* __restrict__ C,
                                          int m_blk, int n_blk,
                                          u16* As, u16* Bs) {
    const int tid = threadIdx.x;
    const int wave = tid >> 6, lane = tid & 63;
    const int quad = lane >> 4, l16 = lane & 15;
    const int w_m = (wave >> 1) * 64, w_n = (wave & 1) * 64;
    const int srow = wave * 32;
    const int lrow = lane >> 3;                       // 0..7
    const int csw = ((lane & 7) ^ lrow) * 8;          // swizzled src chunk
    const int rsw = l16 & 7;                          // reader chunk xor
    f32x4 acc[4][4] = {};

    const u16* pa = A + (size_t)(m_blk + srow + lrow) * DIM_ + csw;
    const u16* pb = W + (size_t)(n_blk + srow + lrow) * DIM_ + csw;

    for (int k0 = 0; k0 < DIM_; k0 += 64) {
        #pragma unroll
        for (int i = 0; i < 4; ++i) {
            g2l16(pa + k0 + i * 8 * DIM_, As + (srow + i * 8) * 64);
            g2l16(pb + k0 + i * 8 * DIM_, Bs + (srow + i * 8) * 64);
        }
        __syncthreads();          // staging visible
        #pragma unroll
        for (int kk = 0; kk < 2; ++kk) {
            bf16x8 af[4], bf[4];
            #pragma unroll
            for (int mt = 0; mt < 4; ++mt)
                af[mt] = *(const bf16x8*)&As[(w_m + mt * 16 + l16) * 64
                                             + ((kk * 4 + quad) ^ rsw) * 8];
            #pragma unroll
            for (int nt = 0; nt < 4; ++nt)
                bf[nt] = *(const bf16x8*)&Bs[(w_n + nt * 16 + l16) * 64
                                             + ((kk * 4 + quad) ^ rsw) * 8];
            #pragma unroll
            for (int mt = 0; mt < 4; ++mt)
                #pragma unroll
                for (int nt = 0; nt < 4; ++nt)
                    acc[mt][nt] = mfma16(af[mt], bf[nt], acc[mt][nt]);
        }
        __syncthreads();          // frag reads done before next staging
    }
    #pragma unroll
    for (int nt = 0; nt < 4; ++nt) {
        int col = n_blk + w_n + nt * 16 + l16;
        float bv = bias[col];
        #pragma unroll
        for (int mt = 0; mt < 4; ++mt) {
            #pragma unroll
            for (int r = 0; r < 4; ++r) {
                int row = m_blk + w_m + mt * 16 + quad * 4 + r;
                float v = acc[mt][nt][r] + bv;
                if constexpr (sizeof(OT) == 4) C[(size_t)row * DIM_ + col] = v;
                else C[(size_t)row * DIM_ + col] = (OT)f2bf(v);
            }
        }
    }
}

// ------- 256x256 8-phase GEMM core (T3+T4+T5 + conflict-free swizzle) -------
// 512 threads = 8 waves (2M x 4N). BK=64 split in two K=32 half-planes.
// Fragment reads are INLINE-ASM ds_read_b128 (opaque to the compiler) so no
// automatic s_waitcnt vmcnt(0) drain is inserted before them; the counted
// vmcnt(4) at every odd phase is the only (and sufficient) staging guarantee:
//   prologue leaves the two k1 half-planes outstanding; each odd-phase
//   vmcnt(4) retires exactly the 4 loads (A+B half-plane pair) that the next
//   two phases read; the final tile drains with vmcnt(0) at ph1.
__device__ __forceinline__ void gemm256_core(const u16* __restrict__ A,
                                             const u16* __restrict__ W,
                                             const float* __restrict__ bias,
                                             u16* __restrict__ C,
                                             int m_blk, int n_blk,
                                             u16* sm) {
    const int tid = threadIdx.x;
    const int wave = tid >> 6, lane = tid & 63;
    const int quad = lane >> 4, l16 = lane & 15;
    const int wr = wave >> 2, wc = wave & 3;
    const int rsw = (l16 >> 1) & 3;
    const unsigned smb = lds_off(sm);
    const unsigned aB = smb + ((wr * 128 + l16) * 32 + (quad ^ rsw) * 8) * 2;
    const unsigned bB = smb + (16384 + (wc * 64 + l16) * 32 + (quad ^ rsw) * 8) * 2;
    const int csw = ((lane & 3) ^ ((lane >> 3) & 3)) * 8;   // staging src swizzle
    const int sdst = wave * 1024;                           // wave's 32-row slab
    const u16* pa = A + (size_t)(m_blk + wave * 32 + (lane >> 2)) * DIM_ + csw;
    const u16* pb = W + (size_t)(n_blk + wave * 32 + (lane >> 2)) * DIM_ + csw;

    f32x4 acc[8][4] = {};

    // prologue: stage tile 0, k0 halves first (8 loads/wave)
    #pragma unroll
    for (int kk = 0; kk < 2; ++kk) {
        #pragma unroll
        for (int i = 0; i < 2; ++i) {
            g2l16(pa + kk * 32 + i * 16 * DIM_, sm + kk * 8192 + sdst + i * 512);
            g2l16(pb + kk * 32 + i * 16 * DIM_,
                  sm + 16384 + kk * 8192 + sdst + i * 512);
        }
    }
    asm volatile("s_waitcnt vmcnt(4)" ::: "memory");   // k0 halves of tile 0 in
    __builtin_amdgcn_s_barrier();

    const int NT = DIM_ / 64;  // 20 K-tiles
    bf16x8 bf[4];
    for (int t = 0; t < NT; ++t) {
        const int cur = (t & 1) * 32768, nxt = cur ^ 32768;
        const bool st = (t + 1 < NT);
        const u16* pat = pa + (t + 1) * 64;
        const u16* pbt = pb + (t + 1) * 64;
        #pragma unroll
        for (int ph = 0; ph < 4; ++ph) {
            const int kk = ph >> 1, mh = ph & 1;
            // ds-read register subtile via opaque asm (no compiler drains)
            if (mh == 0) {
                #pragma unroll
                for (int nt = 0; nt < 4; ++nt)
                    bf[nt] = ldsr128(bB + (cur + kk * 8192 + nt * 512) * 2);
            }
            bf16x8 af[4];
            #pragma unroll
            for (int i = 0; i < 4; ++i)
                af[i] = ldsr128(aB + (cur + kk * 8192 + (mh * 4 + i) * 512) * 2);
            // stage one half-plane of tile t+1 (2 x global_load_lds)
            if (st) {
                const u16* ps = (mh == 0) ? pat : pbt;
                #pragma unroll
                for (int i = 0; i < 2; ++i)
                    g2l16(ps + kk * 32 + i * 16 * DIM_,
                          sm + nxt + mh * 16384 + kk * 8192 + sdst + i * 512);
            }
            __builtin_amdgcn_s_barrier();
            asm volatile("s_waitcnt lgkmcnt(0)" ::: "memory");
            __builtin_amdgcn_sched_barrier(0);   // rule 18: pin MFMA below wait
            __builtin_amdgcn_s_setprio(1);
            #pragma unroll
            for (int i = 0; i < 4; ++i)
                #pragma unroll
                for (int nt = 0; nt < 4; ++nt)
                    acc[mh * 4 + i][nt] = mfma16(af[i], bf[nt], acc[mh * 4 + i][nt]);
            __builtin_amdgcn_s_setprio(0);
            if (ph & 1) {
                // counted wait: retires exactly the half-plane pair the next
                // two phases read; always leaves 4 loads in flight
                if (st) asm volatile("s_waitcnt vmcnt(4)" ::: "memory");
                else if (ph == 1) asm volatile("s_waitcnt vmcnt(0)" ::: "memory");
            }
            __builtin_amdgcn_s_barrier();
        }
    }
    // epilogue: bias + bf16 store
    #pragma unroll
    for (int nt = 0; nt < 4; ++nt) {
        int col = n_blk + wc * 64 + nt * 16 + l16;
        float bv = bias[col];
        #pragma unroll
        for (int mt = 0; mt < 8; ++mt) {
            int row = m_blk + wr * 128 + mt * 16 + quad * 4;
            #pragma unroll
            for (int r = 0; r < 4; ++r)
                C[(size_t)(row + r) * DIM_ + col] = f2bf(acc[mt][nt][r] + bv);
        }
    }
}

// grid 240 = 16 m-tiles x 15 n-tiles (3 weights x 5); XCD-chunked: each XCD
// owns 2 m-tiles x all 15 n-tiles so its 2 A-panels (1.3MB) stay L2-hot.
__global__ __launch_bounds__(512, 2) void qkv_gemm(const u16* __restrict__ xb,
                                                   const u16* __restrict__ Wqb,
                                                   const u16* __restrict__ Wkb,
                                                   const u16* __restrict__ Wvb,
                                                   const float* __restrict__ bq,
                                                   const float* __restrict__ bk,
                                                   const float* __restrict__ bv,
                                                   u16* __restrict__ Qb,
                                                   u16* __restrict__ Kb,
                                                   u16* __restrict__ Vb) {
    __shared__ alignas(16) u16 sm[65536];     // 128 KiB: 2 dbuf x (A+B) x 2 kk
    int id = blockIdx.x;
    int xcd = id & 7, pid = id >> 3;          // pid 0..29
    int m = xcd * 2 + pid / 15;               // 0..15
    int ns = pid % 15;                        // 0..14
    int wsel = ns / 5, n_blk = (ns % 5) * 256;
    const u16* W = (wsel == 0) ? Wqb : (wsel == 1) ? Wkb : Wvb;
    const float* bias = (wsel == 0) ? bq : (wsel == 1) ? bk : bv;
    u16* C = (wsel == 0) ? Qb : (wsel == 1) ? Kb : Vb;
    gemm256_core(xb, W, bias, C, m * 256, n_blk, sm);
}

// flat grid 320; per-XCD patch = 10 W-tiles + 4 AO-tiles (~4.6MB, L2-resident)
__global__ __launch_bounds__(256) void out_gemm(const u16* __restrict__ AO,
                                                const u16* __restrict__ Wob,
                                                const float* __restrict__ bo,
                                                float* __restrict__ C) {
    __shared__ alignas(16) u16 As[128 * 64];
    __shared__ alignas(16) u16 Bs[128 * 64];
    int id = blockIdx.x;
    int xcd = id & 7, pid = id >> 3;          // pid 0..39
    int n = pid % 10;                         // 0..9
    int m = xcd * 4 + pid / 10;               // 0..31
    gemm_core<float>(AO, Wob, bo, C, m * 128, n * 128, As, Bs);
}

// -------- RoPE: Q -> linear Qd (pre-scaled); K -> fragment-packed Kp --------
__global__ __launch_bounds__(256) void rope_k(const u16* __restrict__ Qs_,
                                              const u16* __restrict__ Ks_,
                                              u16* __restrict__ Qd,
                                              u16* __restrict__ Kp,
                                              const float* __restrict__ ct,
                                              const float* __restrict__ st,
                                              float qscale) {
    int t = blockIdx.x * 256 + threadIdx.x;     // 2*NR*8 threads total
    const int NR = B_ * SEQ_ * NH_;
    int rid = t >> 3, j0 = (t & 7) * 8;
    const bool isQ = (rid < NR);
    const u16* src = isQ ? Qs_ : Ks_;
    float sc = isQ ? qscale : 1.0f;
    if (!isQ) rid -= NR;
    int h = rid % NH_;
    int s = (rid / NH_) % SEQ_;
    int b = rid / (NH_ * SEQ_);
    const u16* p = src + (size_t)rid * HD_ + 2 * j0;
    union { uint4 q; u16 u[8]; } a0, a1, o1, o2;
    a0.q = *(const uint4*)p;
    a1.q = *(const uint4*)(p + 8);
    const float* cc = ct + (size_t)s * 64 + j0;
    const float* ss = st + (size_t)s * 64 + j0;
    #pragma unroll
    for (int j = 0; j < 8; ++j) {
        float x1 = bf2f((j < 4) ? a0.u[2 * j] : a1.u[2 * j - 8]);
        float x2 = bf2f((j < 4) ? a0.u[2 * j + 1] : a1.u[2 * j - 7]);
        float c = cc[j], sn = ss[j];
        o1.u[j] = f2bf((x1 * c - x2 * sn) * sc);
        o2.u[j] = f2bf((x1 * sn + x2 * c) * sc);
    }
    if (isQ) {
        u16* q = Qd + (size_t)(((size_t)b * SEQ_ + s) * NH_ + h) * HD_;
        *(uint4*)(q + j0) = o1.q;
        *(uint4*)(q + 64 + j0) = o2.q;
    } else {
        int kt = s >> 6, key = s & 63, nt = key >> 4, l16k = key & 15;
        int qd = (j0 >> 3) & 3;
        int kk1 = j0 >> 5, kk2 = 2 + kk1;
        u16* tb = Kp + ((size_t)((b * NH_ + h) * 32 + kt)) * 8192;
        int lane = qd * 16 + l16k;
        *(uint4*)(tb + (kk1 * 4 + nt) * 512 + lane * 8) = o1.q;
        *(uint4*)(tb + (kk2 * 4 + nt) * 512 + lane * 8) = o2.q;
    }
}

// ---- V transpose -> fragment-packed Vp ----
__global__ __launch_bounds__(256) void transpose_v(const u16* __restrict__ V,
                                                   u16* __restrict__ Vp) {
    __shared__ u16 T[128][72];
    int stile = blockIdx.x, h = blockIdx.y, b = blockIdx.z;
    int tid = threadIdx.x;
    {
        int sl = tid >> 2, d0 = (tid & 3) * 32;
        const u16* vp = V + ((size_t)((b * SEQ_ + stile * 64 + sl) * NH_ + h)) * HD_ + d0;
        #pragma unroll
        for (int i = 0; i < 4; ++i) {
            union { uint4 q; u16 u[8]; } r;
            r.q = *(const uint4*)(vp + i * 8);
            #pragma unroll
            for (int j = 0; j < 8; ++j) T[d0 + i * 8 + j][sl] = r.u[j];
        }
    }
    __syncthreads();
    {
        int d = tid >> 1, kc = (tid & 1) * 32;
        int dt = d >> 4, l16v = d & 15, kk = kc >> 5;
        u16* tb = Vp + ((size_t)((b * NH_ + h) * 32 + stile)) * 8192 + (kk * 8 + dt) * 512;
        #pragma unroll
        for (int i = 0; i < 4; ++i)
            *(uint4*)(tb + (i * 16 + l16v) * 8) = *(const uint4*)&T[d][kc + i * 8];
    }
}

// ---- split-K flash attention, fixed-max softmax (R11-proven version) ----
__device__ const unsigned char QT_TAB[40] =
    {0,1,2,3,4,4,5,5,6,6,7,7,8,8,8,9,9,9,10,10,10,11,11,11,
     12,12,12,12,13,13,13,13,14,14,14,14,15,15,15,15};
__device__ const unsigned char CH_TAB[40] =
    {0,0,0,0,0,1,0,1,0,1,0,1,0,1,2,0,1,2,0,1,2,0,1,2,
     0,1,2,3,0,1,2,3,0,1,2,3,0,1,2,3};

__global__ __launch_bounds__(256, 3) void attn_k(const u16* __restrict__ Q,
                                                 const u16* __restrict__ Kp,
                                                 const u16* __restrict__ Vp,
                                                 u16* __restrict__ AO,
                                                 u16* __restrict__ PO,
                                                 float* __restrict__ Pl) {
    const int cid = blockIdx.x, h = blockIdx.y, b = blockIdx.z;
    const int qt = QT_TAB[cid], c = CH_TAB[cid];
    const int ntiles = 2 * qt + 2;
    const int nch = (ntiles + 7) >> 3;
    const int kt0 = c * 8;
    const int kt1 = (kt0 + 8 < ntiles) ? kt0 + 8 : ntiles;
    const int bh = b * NH_ + h;

    const int tid = threadIdx.x, wave = tid >> 6, lane = tid & 63;
    const int quad = lane >> 4, l16 = lane & 15;

    __shared__ alignas(16) u16 Ks[16 * 512];     // packed K tile, 16 KB
    __shared__ alignas(16) u16 Vs[16 * 512];     // packed V tile, 16 KB
    __shared__ alignas(16) u16 Pt[4][4][512];    // per-wave P^T B-frags, 16 KB

    bf16x8 qf[2][4];
    #pragma unroll
    for (int mt = 0; mt < 2; ++mt) {
        int sq = qt * 128 + wave * 32 + mt * 16 + l16;
        const u16* qp = Q + ((size_t)((b * SEQ_ + sq) * NH_ + h)) * HD_;
        #pragma unroll
        for (int kk = 0; kk < 4; ++kk)
            qf[mt][kk] = *(const bf16x8*)(qp + kk * 32 + quad * 8);
    }
    f32x4 oacc[2][8] = {};
    float l_run[2] = {0.f, 0.f};   // per-lane partial (this quad's keys only)
    const int q0 = qt * 128 + wave * 32 + l16;

    const u16* kpb = Kp + ((size_t)bh * 32) * 8192;
    const u16* vpb = Vp + ((size_t)bh * 32) * 8192;

    for (int kt = kt0; kt < kt1; ++kt) {
        const u16* kp_t = kpb + (size_t)kt * 8192;
        const u16* vp_t = vpb + (size_t)kt * 8192;
        #pragma unroll
        for (int i = 0; i < 4; ++i) {
            int f = wave * 4 + i;
            g2l16(kp_t + f * 512 + lane * 8, &Ks[f * 512]);
            g2l16(vp_t + f * 512 + lane * 8, &Vs[f * 512]);
        }
        __syncthreads();
        f32x4 sacc[2][4] = {};
        #pragma unroll
        for (int kk = 0; kk < 4; ++kk) {
            #pragma unroll
            for (int nt = 0; nt < 4; ++nt) {
                bf16x8 kf = *(const bf16x8*)&Ks[(kk * 4 + nt) * 512 + lane * 8];
                sacc[0][nt] = mfma16(kf, qf[0][kk], sacc[0][nt]);
                sacc[1][nt] = mfma16(kf, qf[1][kk], sacc[1][nt]);
            }
        }
        const bool maskt = (kt >= 2 * qt);
        const int keyb = kt * 64 + quad * 4;
        #pragma unroll
        for (int mt = 0; mt < 2; ++mt) {
            const int qg = q0 + mt * 16;
            float ps = 0.f;
            #pragma unroll
            for (int nt = 0; nt < 4; ++nt) {
                float p[4];
                #pragma unroll
                for (int r = 0; r < 4; ++r) {
                    float x = sacc[mt][nt][r] - 32.0f;
                    if (maskt && (keyb + nt * 16 + r > qg)) x = -INFINITY;
                    p[r] = __builtin_amdgcn_exp2f(x);
                    ps += p[r];
                }
                ushort4 w4 = pack4(p[0], p[1], p[2], p[3]);
                int rowf = (((nt & 1) << 1) | (quad >> 1)) * 16 + l16;
                *(ushort4*)&Pt[wave][mt * 2 + (nt >> 1)][rowf * 8 + (quad & 1) * 4] = w4;
            }
            l_run[mt] += ps;
        }
        // O^T += V^T P^T (no rescale needed: fixed max)
        #pragma unroll
        for (int kk = 0; kk < 2; ++kk) {
            bf16x8 pf0 = *(const bf16x8*)&Pt[wave][kk][(quad * 16 + l16) * 8];
            bf16x8 pf1 = *(const bf16x8*)&Pt[wave][2 + kk][(quad * 16 + l16) * 8];
            #pragma unroll
            for (int dt = 0; dt < 8; ++dt) {
                bf16x8 vf = *(const bf16x8*)&Vs[(kk * 8 + dt) * 512 + lane * 8];
                oacc[0][dt] = mfma16(vf, pf0, oacc[0][dt]);
                oacc[1][dt] = mfma16(vf, pf1, oacc[1][dt]);
            }
        }
        __syncthreads();
    }
    // final l reduction across quads (deferred from the K-loop)
    #pragma unroll
    for (int mt = 0; mt < 2; ++mt) {
        l_run[mt] += __shfl_xor(l_run[mt], 16, 64);
        l_run[mt] += __shfl_xor(l_run[mt], 32, 64);
    }
    if (nch == 1) {
        #pragma unroll
        for (int mt = 0; mt < 2; ++mt) {
            float invl = 1.0f / l_run[mt];
            int sq = q0 + mt * 16;
            u16* op = AO + ((size_t)((b * SEQ_ + sq) * NH_ + h)) * HD_ + quad * 4;
            #pragma unroll
            for (int dt = 0; dt < 8; ++dt) {
                ushort4 w4 = pack4(oacc[mt][dt][0] * invl, oacc[mt][dt][1] * invl,
                                   oacc[mt][dt][2] * invl, oacc[mt][dt][3] * invl);
                *(ushort4*)(op + dt * 16) = w4;
            }
        }
    } else {
        size_t pidx = ((size_t)bh * 16 + qt) * 4 + c;
        u16* po = PO + pidx * 16384;
        #pragma unroll
        for (int mt = 0; mt < 2; ++mt) {
            #pragma unroll
            for (int dt = 0; dt < 8; ++dt) {
                ushort4 w4 = pack4(oacc[mt][dt][0], oacc[mt][dt][1],
                                   oacc[mt][dt][2], oacc[mt][dt][3]);
                *(ushort4*)(po + ((wave * 16 + mt * 8 + dt) * 64 + lane) * 4) = w4;
            }
            if (quad == 0)
                Pl[pidx * 128 + wave * 32 + mt * 16 + l16] = l_run[mt];
        }
    }
}

// ---- combine partials for qt >= 4 (fixed max: plain sums) ----
__global__ __launch_bounds__(256) void combine_k(const u16* __restrict__ PO,
                                                 const float* __restrict__ Pl,
                                                 u16* __restrict__ AO) {
    const int qt = 4 + blockIdx.x, h = blockIdx.y, b = blockIdx.z;
    const int nch = (2 * qt + 2 + 7) >> 3;
    const int bh = b * NH_ + h;
    const int tid = threadIdx.x;
    const int q = tid >> 1, dh = tid & 1;
    const int wave = q >> 5, mt = (q >> 4) & 1, l16 = q & 15;
    size_t base = ((size_t)bh * 16 + qt) * 4;

    float L = 0.f;
    for (int c = 0; c < nch; ++c) L += Pl[(base + c) * 128 + q];
    float o[64];
    #pragma unroll
    for (int j = 0; j < 64; ++j) o[j] = 0.f;
    for (int c = 0; c < nch; ++c) {
        const u16* p = PO + (base + c) * 16384;
        #pragma unroll
        for (int dtl = 0; dtl < 4; ++dtl) {
            int dt = dh * 4 + dtl;
            #pragma unroll
            for (int quad = 0; quad < 4; ++quad) {
                union { ushort4 v; u16 u[4]; } t;
                t.v = *(const ushort4*)(p + ((wave * 16 + mt * 8 + dt) * 64
                                             + quad * 16 + l16) * 4);
                #pragma unroll
                for (int r = 0; r < 4; ++r)
                    o[dtl * 16 + quad * 4 + r] += bf2f(t.u[r]);
            }
        }
    }
    float invL = 1.0f / L;
    int sq = qt * 128 + q;
    u16* op = AO + ((size_t)((b * SEQ_ + sq) * NH_ + h)) * HD_ + dh * 64;
    union { uint4 v[8]; u16 u[64]; } t;
    #pragma unroll
    for (int j = 0; j < 64; ++j) t.u[j] = f2bf(o[j] * invL);
    #pragma unroll
    for (int i = 0; i < 8; ++i) *(uint4*)(op + i * 8) = t.v[i];
}

extern "C" void kernel_launch(void* const* d_in, const int* in_sizes, int n_in,
                              void* d_out, int out_size, void* d_ws, size_t ws_size,
                              hipStream_t stream) {
    const float* x  = (const float*)d_in[0];
    const float* Wq = (const float*)d_in[2];
    const float* bq = (const float*)d_in[3];
    const float* Wk = (const float*)d_in[4];
    const float* bk = (const float*)d_in[5];
    const float* Wv = (const float*)d_in[6];
    const float* bv = (const float*)d_in[7];
    const float* Wo = (const float*)d_in[8];
    const float* bo = (const float*)d_in[9];
    float* out = (float*)d_out;

    const size_t NE = (size_t)B_ * SEQ_ * NH_ * HD_;  // 5,242,880
    const size_t WN = (size_t)DIM_ * DIM_;            // 1,638,400
    u16* Qb  = (u16*)d_ws;         // raw Q -> later AO
    u16* Kb  = Qb + NE;            // raw K
    u16* Vb  = Kb + NE;            // raw V -> later Qr (roped Q)
    u16* Vp  = Vb + NE;            // fragment-packed V
    u16* xb  = Vp + NE;            // x bf16 -> later Kp (packed roped K)
    u16* Wqb = xb + NE;
    u16* Wkb = Wqb + WN;
    u16* Wvb = Wkb + WN;
    u16* Wob = Wvb + WN;
    float* ct = (float*)(Wob + WN);
    float* st = ct + (size_t)SEQ_ * 64;
    u16* PO  = (u16*)(st + (size_t)SEQ_ * 64);        // 1280 chunks x 16384 u16
    float* Pl = (float*)(PO + (size_t)B_ * NH_ * 16 * 4 * 16384);
    u16* Qr = Vb;   // roped Q (Vb dead after transpose_v)
    u16* Kp = xb;   // packed roped K (xb dead after qkv_gemm)
    u16* AO = Qb;   // attention output (Qb dead after rope_k)

    const int NCVT = (B_ * SEQ_ * DIM_ + 4 * (int)WN) / 8 / 256;  // 5760
    cvt_k<<<NCVT + 512, 256, 0, stream>>>(x, Wq, Wk, Wv, Wo,
                                          xb, Wqb, Wkb, Wvb, Wob, ct, st);

    qkv_gemm<<<dim3(240), 512, 0, stream>>>(xb, Wqb, Wkb, Wvb, bq, bk, bv,
                                            Qb, Kb, Vb);

    transpose_v<<<dim3(SEQ_ / 64, NH_, B_), 256, 0, stream>>>(Vb, Vp);

    const float qsc = 0.08838834764831845f * 1.4426950408889634f;
    rope_k<<<(2 * B_ * SEQ_ * NH_ * 8) / 256, 256, 0, stream>>>(Qb, Kb, Qr, Kp,
                                                                ct, st, qsc);

    attn_k<<<dim3(40, NH_, B_), 256, 0, stream>>>(Qr, Kp, Vp, AO, PO, Pl);
    combine_k<<<dim3(12, NH_, B_), 256, 0, stream>>>(PO, Pl, AO);

    out_gemm<<<dim3(320), 256, 0, stream>>>(AO, Wob, bo, out);
}

// Round 3
// 246.103 us; speedup vs baseline: 1.0215x; 1.0215x over previous
//
#include <hip/hip_runtime.h>
#include <cmath>

typedef unsigned short u16;
typedef __attribute__((ext_vector_type(8))) short bf16x8;
typedef __attribute__((ext_vector_type(4))) float f32x4;

#define B_    2
#define SEQ_  2048
#define NH_   10
#define HD_   128
#define DIM_  1280

__device__ __forceinline__ u16 f2bf(float f) {
    union { float f; unsigned u; } v; v.f = f;
    unsigned r = (v.u + 0x7fffu + ((v.u >> 16) & 1u)) >> 16;
    return (u16)r;
}
__device__ __forceinline__ float bf2f(u16 h) {
    union { unsigned u; float f; } v; v.u = ((unsigned)h) << 16;
    return v.f;
}
__device__ __forceinline__ f32x4 mfma16(bf16x8 a, bf16x8 b, f32x4 c) {
    return __builtin_amdgcn_mfma_f32_16x16x32_bf16(a, b, c, 0, 0, 0);
}
__device__ __forceinline__ void g2l16(const void* g, void* l) {
    __builtin_amdgcn_global_load_lds(
        (const __attribute__((address_space(1))) unsigned*)g,
        (__attribute__((address_space(3))) unsigned*)l, 16, 0, 0);
}
__device__ __forceinline__ ushort4 pack4(float a, float b, float c, float d) {
    ushort4 w; w.x = f2bf(a); w.y = f2bf(b); w.z = f2bf(c); w.w = f2bf(d);
    return w;
}
// opaque LDS read: ordering vs global_load_lds / other waves is OUR job
// (counted lgkmcnt/vmcnt + barriers). DS ops return in order per wave.
__device__ __forceinline__ bf16x8 ldsr128(unsigned byte_off) {
    bf16x8 r;
    asm volatile("ds_read_b128 %0, %1" : "=v"(r) : "v"(byte_off));
    return r;
}
__device__ __forceinline__ unsigned lds_off(const void* p) {
    return (unsigned)(unsigned long long)
        (__attribute__((address_space(3))) const void*)p;
}

// counted waits; sched_barrier(0) pins the following MFMAs below the wait
// (rule 18: "memory" clobber does not order register-only MFMAs).
#define LGKM(n) do { asm volatile("s_waitcnt lgkmcnt(" #n ")" ::: "memory"); \
                     __builtin_amdgcn_sched_barrier(0); } while (0)
#define VMC(n)  asm volatile("s_waitcnt vmcnt(" #n ")" ::: "memory")

// ---- merged convert + sincos: x + 4 weights -> bf16, then ct/st tables ----
__global__ __launch_bounds__(256) void cvt_k(const float* __restrict__ x,
                                             const float* __restrict__ w0,
                                             const float* __restrict__ w1,
                                             const float* __restrict__ w2,
                                             const float* __restrict__ w3,
                                             u16* __restrict__ xb,
                                             u16* __restrict__ d0,
                                             u16* __restrict__ d1,
                                             u16* __restrict__ d2,
                                             u16* __restrict__ d3,
                                             float* __restrict__ ct,
                                             float* __restrict__ st) {
    const int NX = B_ * SEQ_ * DIM_;          // 5,242,880
    const int WN = DIM_ * DIM_;               // 1,638,400
    const int NCV = (NX + 4 * WN) / 8 / 256;  // 5760 convert blocks
    int bid = blockIdx.x;
    if (bid >= NCV) {                          // sincos tail: 512 blocks
        int idx = (bid - NCV) * 256 + threadIdx.x;
        int s = idx >> 6, j = idx & 63;
        float e = (float)j * (1.0f / 64.0f);
        float theta = 1.0f / powf(10000.0f, e);
        float ang = (float)s * theta;
        ct[idx] = cosf(ang);
        st[idx] = sinf(ang);
        return;
    }
    int i = (bid * 256 + threadIdx.x) * 8;
    const float* src; u16* dst; int off;
    if (i < NX) { src = x; dst = xb; off = i; }
    else {
        int j = i - NX; int w = j / WN; off = j - w * WN;
        src = (w == 0) ? w0 : (w == 1) ? w1 : (w == 2) ? w2 : w3;
        dst = (w == 0) ? d0 : (w == 1) ? d1 : (w == 2) ? d2 : d3;
    }
    float4 a0 = *(const float4*)(src + off);
    float4 a1 = *(const float4*)(src + off + 4);
    union { uint4 q; u16 u[8]; } t;
    t.u[0] = f2bf(a0.x); t.u[1] = f2bf(a0.y);
    t.u[2] = f2bf(a0.z); t.u[3] = f2bf(a0.w);
    t.u[4] = f2bf(a1.x); t.u[5] = f2bf(a1.y);
    t.u[6] = f2bf(a1.z); t.u[7] = f2bf(a1.w);
    *(uint4*)(dst + off) = t.q;
}

// ------- legacy GEMM core (kept for out_gemm): 128x128 tile, BK=64 -------
template <typename OT>
__device__ __forceinline__ void gemm_core(const u16* __restrict__ A,
                                          const u16* __restrict__ W,
                                          const float* __restrict__ bias,
                                          OT* __restrict__ C,
                                          int m_blk, int n_blk,
                                          u16* As, u16* Bs) {
    const int tid = threadIdx.x;
    const int wave = tid >> 6, lane = tid & 63;
    const int quad = lane >> 4, l16 = lane & 15;
    const int w_m = (wave >> 1) * 64, w_n = (wave & 1) * 64;
    const int srow = wave * 32;
    const int lrow = lane >> 3;                       // 0..7
    const int csw = ((lane & 7) ^ lrow) * 8;          // swizzled src chunk
    const int rsw = l16 & 7;                          // reader chunk xor
    f32x4 acc[4][4] = {};

    const u16* pa = A + (size_t)(m_blk + srow + lrow) * DIM_ + csw;
    const u16* pb = W + (size_t)(n_blk + srow + lrow) * DIM_ + csw;

    for (int k0 = 0; k0 < DIM_; k0 += 64) {
        #pragma unroll
        for (int i = 0; i < 4; ++i) {
            g2l16(pa + k0 + i * 8 * DIM_, As + (srow + i * 8) * 64);
            g2l16(pb + k0 + i * 8 * DIM_, Bs + (srow + i * 8) * 64);
        }
        __syncthreads();          // staging visible
        #pragma unroll
        for (int kk = 0; kk < 2; ++kk) {
            bf16x8 af[4], bf[4];
            #pragma unroll
            for (int mt = 0; mt < 4; ++mt)
                af[mt] = *(const bf16x8*)&As[(w_m + mt * 16 + l16) * 64
                                             + ((kk * 4 + quad) ^ rsw) * 8];
            #pragma unroll
            for (int nt = 0; nt < 4; ++nt)
                bf[nt] = *(const bf16x8*)&Bs[(w_n + nt * 16 + l16) * 64
                                             + ((kk * 4 + quad) ^ rsw) * 8];
            #pragma unroll
            for (int mt = 0; mt < 4; ++mt)
                #pragma unroll
                for (int nt = 0; nt < 4; ++nt)
                    acc[mt][nt] = mfma16(af[mt], bf[nt], acc[mt][nt]);
        }
        __syncthreads();          // frag reads done before next staging
    }
    #pragma unroll
    for (int nt = 0; nt < 4; ++nt) {
        int col = n_blk + w_n + nt * 16 + l16;
        float bv = bias[col];
        #pragma unroll
        for (int mt = 0; mt < 4; ++mt) {
            #pragma unroll
            for (int r = 0; r < 4; ++r) {
                int row = m_blk + w_m + mt * 16 + quad * 4 + r;
                float v = acc[mt][nt][r] + bv;
                if constexpr (sizeof(OT) == 4) C[(size_t)row * DIM_ + col] = v;
                else C[(size_t)row * DIM_ + col] = (OT)f2bf(v);
            }
        }
    }
}

// ------- 256x256 GEMM core: 4 phases/K-tile, 2 barriers/K-tile only -------
// 512 threads = 8 waves (2M x 4N). BK=64 in two K=32 half-planes.
// Sync design (audited ledger):
//  - odd-phase [vmcnt(4); s_barrier] is the ONLY cross-wave guarantee:
//    each wave retires its own 4 oldest DMAs (the A+B half-plane pair the
//    next two phases read), barrier makes it mutual. Even phases have NO
//    barrier -> waves drift, so one wave's lgkm wait overlaps the other
//    SIMD-resident wave's MFMA cluster (separate pipes, m114).
//  - within a phase: reads issued in order bf0..3, af0..3, then counted
//    lgkmcnt(3/2/1/0) interleaved with 4-MFMA groups so matrix work starts
//    as soon as the first fragments land, covering the LDS-pipe backlog.
//  - every WAR (buffer re-stage vs last read) retains >=1 barrier slack.
#define PHASE(KKE, MH, LOADB, PS, LDD)                                        \
  {                                                                           \
    if (LOADB) {                                                              \
      bf[0] = ldsr128(bC + ((KKE) + 0 * 512) * 2);                            \
      bf[1] = ldsr128(bC + ((KKE) + 1 * 512) * 2);                            \
      bf[2] = ldsr128(bC + ((KKE) + 2 * 512) * 2);                            \
      bf[3] = ldsr128(bC + ((KKE) + 3 * 512) * 2);                            \
    }                                                                         \
    bf16x8 af0 = ldsr128(aC + ((KKE) + ((MH) * 4 + 0) * 512) * 2);            \
    bf16x8 af1 = ldsr128(aC + ((KKE) + ((MH) * 4 + 1) * 512) * 2);            \
    bf16x8 af2 = ldsr128(aC + ((KKE) + ((MH) * 4 + 2) * 512) * 2);            \
    bf16x8 af3 = ldsr128(aC + ((KKE) + ((MH) * 4 + 3) * 512) * 2);            \
    if (st) { g2l16((PS), (LDD)); g2l16((PS) + 16 * DIM_, (LDD) + 512); }     \
    __builtin_amdgcn_s_setprio(1);                                            \
    LGKM(3);                                                                  \
    acc[(MH)*4+0][0] = mfma16(af0, bf[0], acc[(MH)*4+0][0]);                  \
    acc[(MH)*4+0][1] = mfma16(af0, bf[1], acc[(MH)*4+0][1]);                  \
    acc[(MH)*4+0][2] = mfma16(af0, bf[2], acc[(MH)*4+0][2]);                  \
    acc[(MH)*4+0][3] = mfma16(af0, bf[3], acc[(MH)*4+0][3]);                  \
    LGKM(2);                                                                  \
    acc[(MH)*4+1][0] = mfma16(af1, bf[0], acc[(MH)*4+1][0]);                  \
    acc[(MH)*4+1][1] = mfma16(af1, bf[1], acc[(MH)*4+1][1]);                  \
    acc[(MH)*4+1][2] = mfma16(af1, bf[2], acc[(MH)*4+1][2]);                  \
    acc[(MH)*4+1][3] = mfma16(af1, bf[3], acc[(MH)*4+1][3]);                  \
    LGKM(1);                                                                  \
    acc[(MH)*4+2][0] = mfma16(af2, bf[0], acc[(MH)*4+2][0]);                  \
    acc[(MH)*4+2][1] = mfma16(af2, bf[1], acc[(MH)*4+2][1]);                  \
    acc[(MH)*4+2][2] = mfma16(af2, bf[2], acc[(MH)*4+2][2]);                  \
    acc[(MH)*4+2][3] = mfma16(af2, bf[3], acc[(MH)*4+2][3]);                  \
    LGKM(0);                                                                  \
    acc[(MH)*4+3][0] = mfma16(af3, bf[0], acc[(MH)*4+3][0]);                  \
    acc[(MH)*4+3][1] = mfma16(af3, bf[1], acc[(MH)*4+3][1]);                  \
    acc[(MH)*4+3][2] = mfma16(af3, bf[2], acc[(MH)*4+3][2]);                  \
    acc[(MH)*4+3][3] = mfma16(af3, bf[3], acc[(MH)*4+3][3]);                  \
    __builtin_amdgcn_s_setprio(0);                                            \
  }

__device__ __forceinline__ void gemm256_core(const u16* __restrict__ A,
                                             const u16* __restrict__ W,
                                             const float* __restrict__ bias,
                                             u16* __restrict__ C,
                                             int m_blk, int n_blk,
                                             u16* sm) {
    const int tid = threadIdx.x;
    const int wave = tid >> 6, lane = tid & 63;
    const int quad = lane >> 4, l16 = lane & 15;
    const int wr = wave >> 2, wc = wave & 3;
    const int rsw = (l16 >> 1) & 3;
    const unsigned smb = lds_off(sm);
    const unsigned aB = smb + ((wr * 128 + l16) * 32 + (quad ^ rsw) * 8) * 2;
    const unsigned bB = smb + (16384 + (wc * 64 + l16) * 32 + (quad ^ rsw) * 8) * 2;
    const int csw = ((lane & 3) ^ ((lane >> 3) & 3)) * 8;   // staging src swizzle
    const int sdst = wave * 1024;                           // wave's 32-row slab
    const u16* pa = A + (size_t)(m_blk + wave * 32 + (lane >> 2)) * DIM_ + csw;
    const u16* pb = W + (size_t)(n_blk + wave * 32 + (lane >> 2)) * DIM_ + csw;

    f32x4 acc[8][4] = {};

    // prologue: stage tile 0, k0 halves first (8 loads/wave)
    #pragma unroll
    for (int kk = 0; kk < 2; ++kk) {
        #pragma unroll
        for (int i = 0; i < 2; ++i) {
            g2l16(pa + kk * 32 + i * 16 * DIM_, sm + kk * 8192 + sdst + i * 512);
            g2l16(pb + kk * 32 + i * 16 * DIM_,
                  sm + 16384 + kk * 8192 + sdst + i * 512);
        }
    }
    VMC(4);                                    // k0 halves of tile 0 landed
    asm volatile("s_waitcnt lgkmcnt(0)" ::: "memory");  // zero lgkm ledger
    __builtin_amdgcn_s_barrier();

    const int NT = DIM_ / 64;  // 20 K-tiles
    bf16x8 bf[4];
    for (int t = 0; t < NT; ++t) {
        const int cur = (t & 1) * 32768, nxt = cur ^ 32768;
        const bool st = (t + 1 < NT);
        const unsigned aC = aB + cur * 2;
        const unsigned bC = bB + cur * 2;
        const u16* pat = pa + (t + 1) * 64;
        const u16* pbt = pb + (t + 1) * 64;

        // ph0: kk0, A rows 0-3; stage A-k0(t+1)
        PHASE(0, 0, true, pat, sm + nxt + sdst);
        // ph1: kk0, A rows 4-7; stage B-k0(t+1)
        PHASE(0, 1, false, pbt, sm + nxt + 16384 + sdst);
        if (st) VMC(4); else VMC(0);   // retire k1-cur pair -> ph2/ph3 safe
        __builtin_amdgcn_s_barrier();
        // ph2: kk1, A rows 0-3; stage A-k1(t+1)
        PHASE(8192, 0, true, pat + 32, sm + nxt + 8192 + sdst);
        // ph3: kk1, A rows 4-7; stage B-k1(t+1)
        PHASE(8192, 1, false, pbt + 32, sm + nxt + 16384 + 8192 + sdst);
        if (st) {
            VMC(4);                    // retire k0-next pair -> next ph0/ph1
            __builtin_amdgcn_s_barrier();
        }
    }
    // epilogue: bias + bf16 store
    #pragma unroll
    for (int nt = 0; nt < 4; ++nt) {
        int col = n_blk + wc * 64 + nt * 16 + l16;
        float bv = bias[col];
        #pragma unroll
        for (int mt = 0; mt < 8; ++mt) {
            int row = m_blk + wr * 128 + mt * 16 + quad * 4;
            #pragma unroll
            for (int r = 0; r < 4; ++r)
                C[(size_t)(row + r) * DIM_ + col] = f2bf(acc[mt][nt][r] + bv);
        }
    }
}

// grid 240 = 16 m-tiles x 15 n-tiles (3 weights x 5); XCD-chunked: each XCD
// owns 2 m-tiles x all 15 n-tiles so its 2 A-panels (1.3MB) stay L2-hot.
__global__ __launch_bounds__(512, 2) void qkv_gemm(const u16* __restrict__ xb,
                                                   const u16* __restrict__ Wqb,
                                                   const u16* __restrict__ Wkb,
                                                   const u16* __restrict__ Wvb,
                                                   const float* __restrict__ bq,
                                                   const float* __restrict__ bk,
                                                   const float* __restrict__ bv,
                                                   u16* __restrict__ Qb,
                                                   u16* __restrict__ Kb,
                                                   u16* __restrict__ Vb) {
    __shared__ alignas(16) u16 sm[65536];     // 128 KiB: 2 dbuf x (A+B) x 2 kk
    int id = blockIdx.x;
    int xcd = id & 7, pid = id >> 3;          // pid 0..29
    int m = xcd * 2 + pid / 15;               // 0..15
    int ns = pid % 15;                        // 0..14
    int wsel = ns / 5, n_blk = (ns % 5) * 256;
    const u16* W = (wsel == 0) ? Wqb : (wsel == 1) ? Wkb : Wvb;
    const float* bias = (wsel == 0) ? bq : (wsel == 1) ? bk : bv;
    u16* C = (wsel == 0) ? Qb : (wsel == 1) ? Kb : Vb;
    gemm256_core(xb, W, bias, C, m * 256, n_blk, sm);
}

// flat grid 320; per-XCD patch = 10 W-tiles + 4 AO-tiles (~4.6MB, L2-resident)
__global__ __launch_bounds__(256) void out_gemm(const u16* __restrict__ AO,
                                                const u16* __restrict__ Wob,
                                                const float* __restrict__ bo,
                                                float* __restrict__ C) {
    __shared__ alignas(16) u16 As[128 * 64];
    __shared__ alignas(16) u16 Bs[128 * 64];
    int id = blockIdx.x;
    int xcd = id & 7, pid = id >> 3;          // pid 0..39
    int n = pid % 10;                         // 0..9
    int m = xcd * 4 + pid / 10;               // 0..31
    gemm_core<float>(AO, Wob, bo, C, m * 128, n * 128, As, Bs);
}

// -------- RoPE: Q -> linear Qd (pre-scaled); K -> fragment-packed Kp --------
__global__ __launch_bounds__(256) void rope_k(const u16* __restrict__ Qs_,
                                              const u16* __restrict__ Ks_,
                                              u16* __restrict__ Qd,
                                              u16* __restrict__ Kp,
                                              const float* __restrict__ ct,
                                              const float* __restrict__ st,
                                              float qscale) {
    int t = blockIdx.x * 256 + threadIdx.x;     // 2*NR*8 threads total
    const int NR = B_ * SEQ_ * NH_;
    int rid = t >> 3, j0 = (t & 7) * 8;
    const bool isQ = (rid < NR);
    const u16* src = isQ ? Qs_ : Ks_;
    float sc = isQ ? qscale : 1.0f;
    if (!isQ) rid -= NR;
    int h = rid % NH_;
    int s = (rid / NH_) % SEQ_;
    int b = rid / (NH_ * SEQ_);
    const u16* p = src + (size_t)rid * HD_ + 2 * j0;
    union { uint4 q; u16 u[8]; } a0, a1, o1, o2;
    a0.q = *(const uint4*)p;
    a1.q = *(const uint4*)(p + 8);
    const float* cc = ct + (size_t)s * 64 + j0;
    const float* ss = st + (size_t)s * 64 + j0;
    #pragma unroll
    for (int j = 0; j < 8; ++j) {
        float x1 = bf2f((j < 4) ? a0.u[2 * j] : a1.u[2 * j - 8]);
        float x2 = bf2f((j < 4) ? a0.u[2 * j + 1] : a1.u[2 * j - 7]);
        float c = cc[j], sn = ss[j];
        o1.u[j] = f2bf((x1 * c - x2 * sn) * sc);
        o2.u[j] = f2bf((x1 * sn + x2 * c) * sc);
    }
    if (isQ) {
        u16* q = Qd + (size_t)(((size_t)b * SEQ_ + s) * NH_ + h) * HD_;
        *(uint4*)(q + j0) = o1.q;
        *(uint4*)(q + 64 + j0) = o2.q;
    } else {
        int kt = s >> 6, key = s & 63, nt = key >> 4, l16k = key & 15;
        int qd = (j0 >> 3) & 3;
        int kk1 = j0 >> 5, kk2 = 2 + kk1;
        u16* tb = Kp + ((size_t)((b * NH_ + h) * 32 + kt)) * 8192;
        int lane = qd * 16 + l16k;
        *(uint4*)(tb + (kk1 * 4 + nt) * 512 + lane * 8) = o1.q;
        *(uint4*)(tb + (kk2 * 4 + nt) * 512 + lane * 8) = o2.q;
    }
}

// ---- V transpose -> fragment-packed Vp ----
__global__ __launch_bounds__(256) void transpose_v(const u16* __restrict__ V,
                                                   u16* __restrict__ Vp) {
    __shared__ u16 T[128][72];
    int stile = blockIdx.x, h = blockIdx.y, b = blockIdx.z;
    int tid = threadIdx.x;
    {
        int sl = tid >> 2, d0 = (tid & 3) * 32;
        const u16* vp = V + ((size_t)((b * SEQ_ + stile * 64 + sl) * NH_ + h)) * HD_ + d0;
        #pragma unroll
        for (int i = 0; i < 4; ++i) {
            union { uint4 q; u16 u[8]; } r;
            r.q = *(const uint4*)(vp + i * 8);
            #pragma unroll
            for (int j = 0; j < 8; ++j) T[d0 + i * 8 + j][sl] = r.u[j];
        }
    }
    __syncthreads();
    {
        int d = tid >> 1, kc = (tid & 1) * 32;
        int dt = d >> 4, l16v = d & 15, kk = kc >> 5;
        u16* tb = Vp + ((size_t)((b * NH_ + h) * 32 + stile)) * 8192 + (kk * 8 + dt) * 512;
        #pragma unroll
        for (int i = 0; i < 4; ++i)
            *(uint4*)(tb + (i * 16 + l16v) * 8) = *(const uint4*)&T[d][kc + i * 8];
    }
}

// ---- split-K flash attention, fixed-max softmax (R11-proven version) ----
__device__ const unsigned char QT_TAB[40] =
    {0,1,2,3,4,4,5,5,6,6,7,7,8,8,8,9,9,9,10,10,10,11,11,11,
     12,12,12,12,13,13,13,13,14,14,14,14,15,15,15,15};
__device__ const unsigned char CH_TAB[40] =
    {0,0,0,0,0,1,0,1,0,1,0,1,0,1,2,0,1,2,0,1,2,0,1,2,
     0,1,2,3,0,1,2,3,0,1,2,3,0,1,2,3};

__global__ __launch_bounds__(256, 3) void attn_k(const u16* __restrict__ Q,
                                                 const u16* __restrict__ Kp,
                                                 const u16* __restrict__ Vp,
                                                 u16* __restrict__ AO,
                                                 u16* __restrict__ PO,
                                                 float* __restrict__ Pl) {
    const int cid = blockIdx.x, h = blockIdx.y, b = blockIdx.z;
    const int qt = QT_TAB[cid], c = CH_TAB[cid];
    const int ntiles = 2 * qt + 2;
    const int nch = (ntiles + 7) >> 3;
    const int kt0 = c * 8;
    const int kt1 = (kt0 + 8 < ntiles) ? kt0 + 8 : ntiles;
    const int bh = b * NH_ + h;

    const int tid = threadIdx.x, wave = tid >> 6, lane = tid & 63;
    const int quad = lane >> 4, l16 = lane & 15;

    __shared__ alignas(16) u16 Ks[16 * 512];     // packed K tile, 16 KB
    __shared__ alignas(16) u16 Vs[16 * 512];     // packed V tile, 16 KB
    __shared__ alignas(16) u16 Pt[4][4][512];    // per-wave P^T B-frags, 16 KB

    bf16x8 qf[2][4];
    #pragma unroll
    for (int mt = 0; mt < 2; ++mt) {
        int sq = qt * 128 + wave * 32 + mt * 16 + l16;
        const u16* qp = Q + ((size_t)((b * SEQ_ + sq) * NH_ + h)) * HD_;
        #pragma unroll
        for (int kk = 0; kk < 4; ++kk)
            qf[mt][kk] = *(const bf16x8*)(qp + kk * 32 + quad * 8);
    }
    f32x4 oacc[2][8] = {};
    float l_run[2] = {0.f, 0.f};   // per-lane partial (this quad's keys only)
    const int q0 = qt * 128 + wave * 32 + l16;

    const u16* kpb = Kp + ((size_t)bh * 32) * 8192;
    const u16* vpb = Vp + ((size_t)bh * 32) * 8192;

    for (int kt = kt0; kt < kt1; ++kt) {
        const u16* kp_t = kpb + (size_t)kt * 8192;
        const u16* vp_t = vpb + (size_t)kt * 8192;
        #pragma unroll
        for (int i = 0; i < 4; ++i) {
            int f = wave * 4 + i;
            g2l16(kp_t + f * 512 + lane * 8, &Ks[f * 512]);
            g2l16(vp_t + f * 512 + lane * 8, &Vs[f * 512]);
        }
        __syncthreads();
        f32x4 sacc[2][4] = {};
        #pragma unroll
        for (int kk = 0; kk < 4; ++kk) {
            #pragma unroll
            for (int nt = 0; nt < 4; ++nt) {
                bf16x8 kf = *(const bf16x8*)&Ks[(kk * 4 + nt) * 512 + lane * 8];
                sacc[0][nt] = mfma16(kf, qf[0][kk], sacc[0][nt]);
                sacc[1][nt] = mfma16(kf, qf[1][kk], sacc[1][nt]);
            }
        }
        const bool maskt = (kt >= 2 * qt);
        const int keyb = kt * 64 + quad * 4;
        #pragma unroll
        for (int mt = 0; mt < 2; ++mt) {
            const int qg = q0 + mt * 16;
            float ps = 0.f;
            #pragma unroll
            for (int nt = 0; nt < 4; ++nt) {
                float p[4];
                #pragma unroll
                for (int r = 0; r < 4; ++r) {
                    float x = sacc[mt][nt][r] - 32.0f;
                    if (maskt && (keyb + nt * 16 + r > qg)) x = -INFINITY;
                    p[r] = __builtin_amdgcn_exp2f(x);
                    ps += p[r];
                }
                ushort4 w4 = pack4(p[0], p[1], p[2], p[3]);
                int rowf = (((nt & 1) << 1) | (quad >> 1)) * 16 + l16;
                *(ushort4*)&Pt[wave][mt * 2 + (nt >> 1)][rowf * 8 + (quad & 1) * 4] = w4;
            }
            l_run[mt] += ps;
        }
        // O^T += V^T P^T (no rescale needed: fixed max)
        #pragma unroll
        for (int kk = 0; kk < 2; ++kk) {
            bf16x8 pf0 = *(const bf16x8*)&Pt[wave][kk][(quad * 16 + l16) * 8];
            bf16x8 pf1 = *(const bf16x8*)&Pt[wave][2 + kk][(quad * 16 + l16) * 8];
            #pragma unroll
            for (int dt = 0; dt < 8; ++dt) {
                bf16x8 vf = *(const bf16x8*)&Vs[(kk * 8 + dt) * 512 + lane * 8];
                oacc[0][dt] = mfma16(vf, pf0, oacc[0][dt]);
                oacc[1][dt] = mfma16(vf, pf1, oacc[1][dt]);
            }
        }
        __syncthreads();
    }
    // final l reduction across quads (deferred from the K-loop)
    #pragma unroll
    for (int mt = 0; mt < 2; ++mt) {
        l_run[mt] += __shfl_xor(l_run[mt], 16, 64);
        l_run[mt] += __shfl_xor(l_run[mt], 32, 64);
    }
    if (nch == 1) {
        #pragma unroll
        for (int mt = 0; mt < 2; ++mt) {
            float invl = 1.0f / l_run[mt];
            int sq = q0 + mt * 16;
            u16* op = AO + ((size_t)((b * SEQ_ + sq) * NH_ + h)) * HD_ + quad * 4;
            #pragma unroll
            for (int dt = 0; dt < 8; ++dt) {
                ushort4 w4 = pack4(oacc[mt][dt][0] * invl, oacc[mt][dt][1] * invl,
                                   oacc[mt][dt][2] * invl, oacc[mt][dt][3] * invl);
                *(ushort4*)(op + dt * 16) = w4;
            }
        }
    } else {
        size_t pidx = ((size_t)bh * 16 + qt) * 4 + c;
        u16* po = PO + pidx * 16384;
        #pragma unroll
        for (int mt = 0; mt < 2; ++mt) {
            #pragma unroll
            for (int dt = 0; dt < 8; ++dt) {
                ushort4 w4 = pack4(oacc[mt][dt][0], oacc[mt][dt][1],
                                   oacc[mt][dt][2], oacc[mt][dt][3]);
                *(ushort4*)(po + ((wave * 16 + mt * 8 + dt) * 64 + lane) * 4) = w4;
            }
            if (quad == 0)
                Pl[pidx * 128 + wave * 32 + mt * 16 + l16] = l_run[mt];
        }
    }
}

// ---- combine partials for qt >= 4 (fixed max: plain sums) ----
__global__ __launch_bounds__(256) void combine_k(const u16* __restrict__ PO,
                                                 const float* __restrict__ Pl,
                                                 u16* __restrict__ AO) {
    const int qt = 4 + blockIdx.x, h = blockIdx.y, b = blockIdx.z;
    const int nch = (2 * qt + 2 + 7) >> 3;
    const int bh = b * NH_ + h;
    const int tid = threadIdx.x;
    const int q = tid >> 1, dh = tid & 1;
    const int wave = q >> 5, mt = (q >> 4) & 1, l16 = q & 15;
    size_t base = ((size_t)bh * 16 + qt) * 4;

    float L = 0.f;
    for (int c = 0; c < nch; ++c) L += Pl[(base + c) * 128 + q];
    float o[64];
    #pragma unroll
    for (int j = 0; j < 64; ++j) o[j] = 0.f;
    for (int c = 0; c < nch; ++c) {
        const u16* p = PO + (base + c) * 16384;
        #pragma unroll
        for (int dtl = 0; dtl < 4; ++dtl) {
            int dt = dh * 4 + dtl;
            #pragma unroll
            for (int quad = 0; quad < 4; ++quad) {
                union { ushort4 v; u16 u[4]; } t;
                t.v = *(const ushort4*)(p + ((wave * 16 + mt * 8 + dt) * 64
                                             + quad * 16 + l16) * 4);
                #pragma unroll
                for (int r = 0; r < 4; ++r)
                    o[dtl * 16 + quad * 4 + r] += bf2f(t.u[r]);
            }
        }
    }
    float invL = 1.0f / L;
    int sq = qt * 128 + q;
    u16* op = AO + ((size_t)((b * SEQ_ + sq) * NH_ + h)) * HD_ + dh * 64;
    union { uint4 v[8]; u16 u[64]; } t;
    #pragma unroll
    for (int j = 0; j < 64; ++j) t.u[j] = f2bf(o[j] * invL);
    #pragma unroll
    for (int i = 0; i < 8; ++i) *(uint4*)(op + i * 8) = t.v[i];
}

extern "C" void kernel_launch(void* const* d_in, const int* in_sizes, int n_in,
                              void* d_out, int out_size, void* d_ws, size_t ws_size,
                              hipStream_t stream) {
    const float* x  = (const float*)d_in[0];
    const float* Wq = (const float*)d_in[2];
    const float* bq = (const float*)d_in[3];
    const float* Wk = (const float*)d_in[4];
    const float* bk = (const float*)d_in[5];
    const float* Wv = (const float*)d_in[6];
    const float* bv = (const float*)d_in[7];
    const float* Wo = (const float*)d_in[8];
    const float* bo = (const float*)d_in[9];
    float* out = (float*)d_out;

    const size_t NE = (size_t)B_ * SEQ_ * NH_ * HD_;  // 5,242,880
    const size_t WN = (size_t)DIM_ * DIM_;            // 1,638,400
    u16* Qb  = (u16*)d_ws;         // raw Q -> later AO
    u16* Kb  = Qb + NE;            // raw K
    u16* Vb  = Kb + NE;            // raw V -> later Qr (roped Q)
    u16* Vp  = Vb + NE;            // fragment-packed V
    u16* xb  = Vp + NE;            // x bf16 -> later Kp (packed roped K)
    u16* Wqb = xb + NE;
    u16* Wkb = Wqb + WN;
    u16* Wvb = Wkb + WN;
    u16* Wob = Wvb + WN;
    float* ct = (float*)(Wob + WN);
    float* st = ct + (size_t)SEQ_ * 64;
    u16* PO  = (u16*)(st + (size_t)SEQ_ * 64);        // 1280 chunks x 16384 u16
    float* Pl = (float*)(PO + (size_t)B_ * NH_ * 16 * 4 * 16384);
    u16* Qr = Vb;   // roped Q (Vb dead after transpose_v)
    u16* Kp = xb;   // packed roped K (xb dead after qkv_gemm)
    u16* AO = Qb;   // attention output (Qb dead after rope_k)

    const int NCVT = (B_ * SEQ_ * DIM_ + 4 * (int)WN) / 8 / 256;  // 5760
    cvt_k<<<NCVT + 512, 256, 0, stream>>>(x, Wq, Wk, Wv, Wo,
                                          xb, Wqb, Wkb, Wvb, Wob, ct, st);

    qkv_gemm<<<dim3(240), 512, 0, stream>>>(xb, Wqb, Wkb, Wvb, bq, bk, bv,
                                            Qb, Kb, Vb);

    transpose_v<<<dim3(SEQ_ / 64, NH_, B_), 256, 0, stream>>>(Vb, Vp);

    const float qsc = 0.08838834764831845f * 1.4426950408889634f;
    rope_k<<<(2 * B_ * SEQ_ * NH_ * 8) / 256, 256, 0, stream>>>(Qb, Kb, Qr, Kp,
                                                                ct, st, qsc);

    attn_k<<<dim3(40, NH_, B_), 256, 0, stream>>>(Qr, Kp, Vp, AO, PO, Pl);
    combine_k<<<dim3(12, NH_, B_), 256, 0, stream>>>(PO, Pl, AO);

    out_gemm<<<dim3(320), 256, 0, stream>>>(AO, Wob, bo, out);
}